// Round 9
// baseline (674.815 us; speedup 1.0000x reference)
//
#include <hip/hip_runtime.h>

// Problem constants (from reference)
#define N_NODES 20000
#define F_IN    512
#define D_H     256
#define E_EDGES 200000
#define L_LAYERS 3
#define T_ETYPES 2

#define NPITCH 264   // LDS row pitch (bf16 elems) for the neigh tile, bank-spread

typedef __attribute__((ext_vector_type(8))) short bf16x8;
typedef __attribute__((ext_vector_type(4))) float f32x4;

__device__ __forceinline__ unsigned short f2b(float f) {
    unsigned int u = __float_as_uint(f);
    u = (u + 0x7FFFu + ((u >> 16) & 1u)) >> 16;   // round-nearest-even
    return (unsigned short)u;
}
__device__ __forceinline__ unsigned int pack2(float a, float b) {
    return (unsigned int)f2b(a) | ((unsigned int)f2b(b) << 16);
}

// ---------------- weight pre-shuffle: fp32 row-major -> bf16 fragment-slab order ----
// For W[NO,K]: slab (n>>7, k>>5) of 128 rows x 32 k is a contiguous 4096-elem block;
// elem (n_local,kk) at ((n_local>>4)&7)<<9 | ((kk>>3)&3)<<7 | (n_local&15)<<3 | (kk&7).
// A wave's 16x32 B-tile t at step s is the 1KB run: slab + (t&7)*512 + lane*8.
__device__ __forceinline__ void shuf_one(const float* s, unsigned short* d,
                                         int NO, int K, int i)
{
    const int matsz = NO * K;
    const int mat = i / matsz;
    const int rem = i - mat * matsz;
    const int n = rem / K;
    const int k = rem - n * K;
    const int dst = mat * matsz + ((n >> 7) * (K >> 5) + (k >> 5)) * 4096
                  + (((n >> 4) & 7) << 9) + (((k >> 3) & 3) << 7)
                  + ((n & 15) << 3) + (k & 7);
    d[dst] = f2b(s[i]);
}

__global__ __launch_bounds__(256) void shufw_kernel(
    const float* __restrict__ s0, unsigned short* __restrict__ d0, int NO0, int K0, int n0,
    const float* __restrict__ s1, unsigned short* __restrict__ d1, int NO1, int K1, int n1,
    const float* __restrict__ s2, unsigned short* __restrict__ d2, int NO2, int K2, int n2,
    const float* __restrict__ s3, unsigned short* __restrict__ d3, int NO3, int K3, int n3)
{
    int i = blockIdx.x * 256 + threadIdx.x;
    if (i < n0) { shuf_one(s0, d0, NO0, K0, i); return; }
    if ((i -= n0) < n1) { shuf_one(s1, d1, NO1, K1, i); return; }
    if ((i -= n1) < n2) { shuf_one(s2, d2, NO2, K2, i); return; }
    if ((i -= n2) < n3) { shuf_one(s3, d3, NO3, K3, i); return; }
}

// ---------------- barrier-free GEMM, fragment-slab weights (lin / pool) ----------------
// C[M, bn:bn+128] = act(A @ W^T + bias). Block 64x128, 4 waves 2x2, wave 32x64.
// NO LDS, NO barriers: A and B fragments both stream global->VGPR (B coalesced 1KB/inst).
template <int A_FP32, int NSTEPS>
__global__ __launch_bounds__(256) void gemm_frag(
    const void* __restrict__ Ap, const unsigned short* __restrict__ Wf,
    const float* __restrict__ bias, unsigned short* __restrict__ Cout,
    int M, int ldc, int relu)
{
    const int K = NSTEPS * 32;
    const int tid  = threadIdx.x;
    const int lane = tid & 63;
    const int w    = tid >> 6;
    const int wm   = w >> 1, wn = w & 1;
    const int bm   = blockIdx.y * 64;
    const int bn   = blockIdx.x * 128;
    const unsigned short* slab0 = Wf + (size_t)blockIdx.x * NSTEPS * 4096;

    const int r0 = min(bm + wm * 32 + (lane & 15), M - 1);
    const int r1 = min(bm + wm * 32 + 16 + (lane & 15), M - 1);
    const int ko = (lane >> 4) << 3;

    f32x4 acc[2][4] = {};

    for (int s = 0; s < NSTEPS; ++s) {
        bf16x8 af0, af1;
        if (A_FP32) {
            const float* p0 = (const float*)Ap + (size_t)r0 * K + s * 32 + ko;
            const float* p1 = (const float*)Ap + (size_t)r1 * K + s * 32 + ko;
            const float4 a0 = *(const float4*)p0, a1 = *(const float4*)(p0 + 4);
            const float4 a2 = *(const float4*)p1, a3 = *(const float4*)(p1 + 4);
            uint4 u0, u1;
            u0.x = pack2(a0.x, a0.y); u0.y = pack2(a0.z, a0.w);
            u0.z = pack2(a1.x, a1.y); u0.w = pack2(a1.z, a1.w);
            u1.x = pack2(a2.x, a2.y); u1.y = pack2(a2.z, a2.w);
            u1.z = pack2(a3.x, a3.y); u1.w = pack2(a3.z, a3.w);
            af0 = *(bf16x8*)&u0; af1 = *(bf16x8*)&u1;
        } else {
            af0 = *(const bf16x8*)((const unsigned short*)Ap + (size_t)r0 * K + s * 32 + ko);
            af1 = *(const bf16x8*)((const unsigned short*)Ap + (size_t)r1 * K + s * 32 + ko);
        }
#pragma unroll
        for (int j = 0; j < 4; ++j) {
            const bf16x8 bf = *(const bf16x8*)(slab0 + s * 4096 + ((wn * 4 + j) << 9) + lane * 8);
            acc[0][j] = __builtin_amdgcn_mfma_f32_16x16x32_bf16(af0, bf, acc[0][j], 0, 0, 0);
            acc[1][j] = __builtin_amdgcn_mfma_f32_16x16x32_bf16(af1, bf, acc[1][j], 0, 0, 0);
        }
    }

    // C/D layout: col = lane&15, row = (lane>>4)*4 + reg
    const int cbase = bn + wn * 64 + (lane & 15);
    const int rbase = bm + wm * 32 + ((lane >> 4) << 2);
#pragma unroll
    for (int j = 0; j < 4; ++j) {
        const int col = cbase + j * 16;
        const float bj = bias[col];
#pragma unroll
        for (int i = 0; i < 2; ++i)
#pragma unroll
            for (int r = 0; r < 4; ++r) {
                const int row = rbase + i * 16 + r;
                if (row < M) {
                    float v = acc[i][j][r] + bj;
                    if (relu) v = fmaxf(v, 0.f);
                    Cout[(size_t)row * ldc + col] = f2b(v);
                }
            }
    }
}

// ---------------- fully fused layer tail: seg-max + dual GEMM (both etypes) + LN sum ----
// Block = 32 dst nodes x 256 cols, 4 waves (wave 32x64 per etype), grid 625 exact.
// Phase 1: seg-max for this block's 32 nodes x 2 etypes, gathered into LDS.
// Phase 2: barrier-free dual GEMM: self A from global h, neigh A from LDS.
// Phase 3: per-etype LN, sum over etypes, write (bf16 h-next or fp32 d_out).
__device__ __forceinline__ ushort4 umax4(ushort4 a, ushort4 b)
{
    a.x = a.x > b.x ? a.x : b.x;
    a.y = a.y > b.y ? a.y : b.y;
    a.z = a.z > b.z ? a.z : b.z;
    a.w = a.w > b.w ? a.w : b.w;
    return a;
}

template <int OUT_FP32>
__global__ __launch_bounds__(256) void sage_tail2(
    const unsigned short* __restrict__ h,      // [N,256] bf16
    const unsigned short* __restrict__ hp,     // [N,512] bf16 (pool output, t*256 cols)
    const int* __restrict__ off,               // CSR offsets, g = t*N + node
    const int* __restrict__ esrc,
    const unsigned short* __restrict__ Wfs,    // [2 mats][2 slabs x 8 steps x 4096]
    const unsigned short* __restrict__ Wfn,
    const float* __restrict__ bias2,           // [2,256]
    const float* __restrict__ gamma2, const float* __restrict__ beta2,
    void* __restrict__ outp, int relu)
{
    __shared__ unsigned short sN[2][32][NPITCH];
    __shared__ float sS[2][4][32], sQ[2][4][32];
    const int tid  = threadIdx.x;
    const int lane = tid & 63;
    const int wv   = tid >> 6;
    const int bm   = blockIdx.x * 32;

    // ---- Phase 1: segment max for 64 (node,etype) tasks, 16 per wave ----
    for (int task = wv * 16; task < wv * 16 + 16; ++task) {
        const int t  = task >> 5;
        const int nl = task & 31;
        const int g  = t * N_NODES + bm + nl;
        const int e0 = off[g], e1 = off[g + 1];
        const int co = t * D_H + lane * 4;
        ushort4 acc = make_ushort4(0, 0, 0, 0);
        int e = e0;
        for (; e + 4 <= e1; e += 4) {
            const int s0 = esrc[e + 0], s1 = esrc[e + 1];
            const int s2 = esrc[e + 2], s3 = esrc[e + 3];
            const ushort4 v0 = *(const ushort4*)(hp + (size_t)s0 * 512 + co);
            const ushort4 v1 = *(const ushort4*)(hp + (size_t)s1 * 512 + co);
            const ushort4 v2 = *(const ushort4*)(hp + (size_t)s2 * 512 + co);
            const ushort4 v3 = *(const ushort4*)(hp + (size_t)s3 * 512 + co);
            acc = umax4(umax4(umax4(acc, v0), umax4(v1, v2)), v3);
        }
        for (; e < e1; ++e)
            acc = umax4(acc, *(const ushort4*)(hp + (size_t)esrc[e] * 512 + co));
        *(ushort4*)&sN[t][nl][lane * 4] = acc;
    }
    __syncthreads();

    // ---- Phase 2: dual GEMM, both etypes; no per-step barriers ----
    const int r0 = bm + (lane & 15);
    const int ko = (lane >> 4) << 3;
    const int rl0 = lane & 15, rl1 = rl0 + 16;

    f32x4 acc[2][2][4] = {};   // [etype][mtile][ntile]

    // self pass: A = h (global), shared by both etypes
#pragma unroll 2
    for (int s = 0; s < 8; ++s) {
        const bf16x8 af0 = *(const bf16x8*)(h + (size_t)r0 * D_H + s * 32 + ko);
        const bf16x8 af1 = *(const bf16x8*)(h + (size_t)(r0 + 16) * D_H + s * 32 + ko);
#pragma unroll
        for (int e = 0; e < 2; ++e)
#pragma unroll
            for (int j = 0; j < 4; ++j) {
                const int tt = wv * 4 + j;
                const bf16x8 bf = *(const bf16x8*)(Wfs + e * 65536
                    + (((tt >> 3) * 8 + s) << 12) + ((tt & 7) << 9) + lane * 8);
                acc[e][0][j] = __builtin_amdgcn_mfma_f32_16x16x32_bf16(af0, bf, acc[e][0][j], 0, 0, 0);
                acc[e][1][j] = __builtin_amdgcn_mfma_f32_16x16x32_bf16(af1, bf, acc[e][1][j], 0, 0, 0);
            }
    }
    // neigh pass: A = seg-max tile in LDS
#pragma unroll 2
    for (int s = 0; s < 8; ++s) {
#pragma unroll
        for (int e = 0; e < 2; ++e) {
            const bf16x8 af0 = *(const bf16x8*)&sN[e][rl0][s * 32 + ko];
            const bf16x8 af1 = *(const bf16x8*)&sN[e][rl1][s * 32 + ko];
#pragma unroll
            for (int j = 0; j < 4; ++j) {
                const int tt = wv * 4 + j;
                const bf16x8 bf = *(const bf16x8*)(Wfn + e * 65536
                    + (((tt >> 3) * 8 + s) << 12) + ((tt & 7) << 9) + lane * 8);
                acc[e][0][j] = __builtin_amdgcn_mfma_f32_16x16x32_bf16(af0, bf, acc[e][0][j], 0, 0, 0);
                acc[e][1][j] = __builtin_amdgcn_mfma_f32_16x16x32_bf16(af1, bf, acc[e][1][j], 0, 0, 0);
            }
        }
    }

    // ---- Phase 3: per-etype LN over 256 cols, sum etypes, write ----
    const int colb = wv * 64 + (lane & 15);
    const int rq   = (lane >> 4) << 2;
    float bia[2][4], gam[2][4], bet[2][4];
#pragma unroll
    for (int e = 0; e < 2; ++e)
#pragma unroll
        for (int j = 0; j < 4; ++j) {
            const int col = colb + j * 16;
            bia[e][j] = bias2[e * D_H + col];
            gam[e][j] = gamma2[e * D_H + col];
            bet[e][j] = beta2[e * D_H + col];
        }
#pragma unroll
    for (int e = 0; e < 2; ++e)
#pragma unroll
        for (int i = 0; i < 2; ++i)
#pragma unroll
            for (int r = 0; r < 4; ++r) {
                float s = 0.f, q = 0.f;
#pragma unroll
                for (int j = 0; j < 4; ++j) {
                    float v = acc[e][i][j][r] + bia[e][j];
                    if (relu) v = fmaxf(v, 0.f);
                    s += v; q += v * v;
                }
#pragma unroll
                for (int o = 1; o < 16; o <<= 1) {
                    s += __shfl_xor(s, o);
                    q += __shfl_xor(q, o);
                }
                if ((lane & 15) == 0) {
                    sS[e][wv][i * 16 + rq + r] = s;
                    sQ[e][wv][i * 16 + rq + r] = q;
                }
            }
    __syncthreads();
#pragma unroll
    for (int i = 0; i < 2; ++i)
#pragma unroll
        for (int r = 0; r < 4; ++r) {
            const int rl = i * 16 + rq + r;
            const int row = bm + rl;
            float mean[2], inv[2];
#pragma unroll
            for (int e = 0; e < 2; ++e) {
                const float st = sS[e][0][rl] + sS[e][1][rl] + sS[e][2][rl] + sS[e][3][rl];
                const float qt = sQ[e][0][rl] + sQ[e][1][rl] + sQ[e][2][rl] + sQ[e][3][rl];
                mean[e] = st * (1.f / 256.f);
                const float var = qt * (1.f / 256.f) - mean[e] * mean[e];
                inv[e] = rsqrtf(var + 1e-5f);
            }
#pragma unroll
            for (int j = 0; j < 4; ++j) {
                const int col = colb + j * 16;
                float o = 0.f;
#pragma unroll
                for (int e = 0; e < 2; ++e) {
                    float v = acc[e][i][j][r] + bia[e][j];
                    if (relu) v = fmaxf(v, 0.f);
                    o += (v - mean[e]) * inv[e] * gam[e][j] + bet[e][j];
                }
                if (OUT_FP32)
                    ((float*)outp)[(size_t)row * D_H + col] = o;
                else
                    ((unsigned short*)outp)[(size_t)row * D_H + col] = f2b(o);
            }
        }
}

// ---------------- CSR build (both etypes batched; once per launch) ----------------
__global__ __launch_bounds__(256) void zero_int_kernel(int* p, int n)
{
    int i = blockIdx.x * 256 + threadIdx.x;
    if (i < n) p[i] = 0;
}

__global__ __launch_bounds__(256) void count_deg_kernel(
    const int* __restrict__ dst, int* __restrict__ cnt, int E2)
{
    int e = blockIdx.x * 256 + threadIdx.x;
    if (e < E2) {
        const int base = (e >= E_EDGES) ? N_NODES : 0;
        atomicAdd(&cnt[base + dst[e]], 1);
    }
}

__global__ __launch_bounds__(256) void scanA_kernel(
    const int* __restrict__ cnt, int* __restrict__ incl, int* __restrict__ bsum, int n)
{
    __shared__ int tmp[256];
    const int tid = threadIdx.x;
    const int i = blockIdx.x * 256 + tid;
    const int v = (i < n) ? cnt[i] : 0;
    tmp[tid] = v;
    __syncthreads();
#pragma unroll
    for (int o = 1; o < 256; o <<= 1) {
        const int t = (tid >= o) ? tmp[tid - o] : 0;
        __syncthreads();
        tmp[tid] += t;
        __syncthreads();
    }
    if (i < n) incl[i] = tmp[tid];
    if (tid == 255) bsum[blockIdx.x] = tmp[255];
}

__global__ __launch_bounds__(256) void scanB_kernel(int* __restrict__ bsum, int nb)
{
    __shared__ int tmp[256];
    const int tid = threadIdx.x;
    const int v = (tid < nb) ? bsum[tid] : 0;
    tmp[tid] = v;
    __syncthreads();
#pragma unroll
    for (int o = 1; o < 256; o <<= 1) {
        const int t = (tid >= o) ? tmp[tid - o] : 0;
        __syncthreads();
        tmp[tid] += t;
        __syncthreads();
    }
    if (tid < nb) bsum[tid] = tmp[tid] - v;  // exclusive
}

__global__ __launch_bounds__(256) void scanC_kernel(
    const int* __restrict__ cnt, const int* __restrict__ incl,
    const int* __restrict__ bsum, int* __restrict__ off, int* __restrict__ cursor, int n)
{
    const int i = blockIdx.x * 256 + threadIdx.x;
    if (i < n) {
        const int e = incl[i] + bsum[blockIdx.x];
        off[i + 1] = e;
        cursor[i] = e - cnt[i];
    }
    if (i == 0) off[0] = 0;
}

__global__ __launch_bounds__(256) void fill_csr_kernel(
    const int* __restrict__ src, const int* __restrict__ dst,
    int* __restrict__ cursor, int* __restrict__ esrc, int E2)
{
    int e = blockIdx.x * 256 + threadIdx.x;
    if (e < E2) {
        const int base = (e >= E_EDGES) ? N_NODES : 0;
        const int pos = atomicAdd(&cursor[base + dst[e]], 1);
        esrc[pos] = src[e];
    }
}

extern "C" void kernel_launch(void* const* d_in, const int* in_sizes, int n_in,
                              void* d_out, int out_size, void* d_ws, size_t ws_size,
                              hipStream_t stream)
{
    const float* x      = (const float*)d_in[0];
    const int*   src    = (const int*)d_in[1];
    const int*   dst    = (const int*)d_in[2];
    const float* Wlin   = (const float*)d_in[3];
    const float* blin   = (const float*)d_in[4];
    const float* Wpool  = (const float*)d_in[5];
    const float* bpool  = (const float*)d_in[6];
    const float* Wself  = (const float*)d_in[7];
    const float* Wneigh = (const float*)d_in[8];
    const float* bconv  = (const float*)d_in[9];
    const float* gamma  = (const float*)d_in[10];
    const float* beta   = (const float*)d_in[11];

    const size_t NB = (size_t)N_NODES * D_H;  // 5.12M
    char* p = (char*)d_ws;
    unsigned short* hp_b    = (unsigned short*)p; p += NB * 2 * T_ETYPES;  // [N,512]
    unsigned short* h_a     = (unsigned short*)p; p += NB * 2;
    unsigned short* h_b     = (unsigned short*)p; p += NB * 2;
    unsigned short* wlin_f  = (unsigned short*)p; p += (size_t)D_H * F_IN * 2;
    const size_t WSZ = (size_t)L_LAYERS * T_ETYPES * D_H * D_H;  // 393216
    unsigned short* wpool_f = (unsigned short*)p; p += WSZ * 2;
    unsigned short* wself_f = (unsigned short*)p; p += WSZ * 2;
    unsigned short* wneigh_f= (unsigned short*)p; p += WSZ * 2;
    int* ip = (int*)p;
    const int NT = T_ETYPES * N_NODES;  // 40000
    int* cnt    = ip; ip += NT;
    int* incl   = ip; ip += NT;
    int* off    = ip; ip += NT + 1;
    int* cursor = ip; ip += NT;
    int* esrc   = ip; ip += T_ETYPES * E_EDGES;
    int* bsum   = ip; ip += 256;

    const dim3 blk(256);
    const int E2 = T_ETYPES * E_EDGES;
    const dim3 e2grid((E2 + 255) / 256);
    const dim3 ntgrid((NT + 255) / 256);
    const int nScanBlk = (NT + 255) / 256;  // 157

    // ---- weights -> bf16 fragment-slab order (one dispatch) ----
    {
        const int nlin = D_H * F_IN;          // 131072, NO=256 K=512
        const int nw   = (int)WSZ;            // 393216
        const int tot  = nlin + 3 * nw;
        shufw_kernel<<<dim3((tot + 255) / 256), blk, 0, stream>>>(
            Wlin, wlin_f, D_H, F_IN, nlin,
            Wpool, wpool_f, T_ETYPES * D_H, D_H, nw,   // per layer: [512,256]
            Wself, wself_f, D_H, D_H, nw,              // per (l,t): [256,256]
            Wneigh, wneigh_f, D_H, D_H, nw);
    }

    // ---- CSR build, both etypes batched ----
    zero_int_kernel<<<ntgrid, blk, 0, stream>>>(cnt, NT);
    count_deg_kernel<<<e2grid, blk, 0, stream>>>(dst, cnt, E2);
    scanA_kernel<<<dim3(nScanBlk), blk, 0, stream>>>(cnt, incl, bsum, NT);
    scanB_kernel<<<dim3(1), blk, 0, stream>>>(bsum, nScanBlk);
    scanC_kernel<<<dim3(nScanBlk), blk, 0, stream>>>(cnt, incl, bsum, off, cursor, NT);
    fill_csr_kernel<<<e2grid, blk, 0, stream>>>(src, dst, cursor, esrc, E2);

    // ---- h0 = bf16(x @ Wlin^T + blin) : fp32 A fused-convert, K=512 ----
    gemm_frag<1, 16><<<dim3(2, (N_NODES + 63) / 64), blk, 0, stream>>>(
        x, wlin_f, blin, h_a, N_NODES, D_H, 0);

    unsigned short* h = h_a;
    unsigned short* hn = h_b;
    const dim3 pgrid(4, (N_NODES + 63) / 64);   // pool: 512 cols batched over etypes
    const dim3 fgrid(N_NODES / 32);             // 625, exact
    for (int l = 0; l < L_LAYERS; ++l) {
        const int relu = (l < L_LAYERS - 1) ? 1 : 0;
        const size_t wo = (size_t)l * T_ETYPES * D_H * D_H;
        const size_t bo = (size_t)l * T_ETYPES * D_H;
        // hp[:, t*256:] = bf16(relu(h @ Wpool[l,t]^T + bpool[l,t])), both t in one dispatch
        gemm_frag<0, 8><<<pgrid, blk, 0, stream>>>(
            h, wpool_f + wo, bpool + bo, hp_b, N_NODES, T_ETYPES * D_H, 1);
        // fused: per-block seg-max + dual GEMM (both etypes) + LN + sum
        if (l < L_LAYERS - 1) {
            sage_tail2<0><<<fgrid, blk, 0, stream>>>(
                h, hp_b, off, esrc, wself_f + wo, wneigh_f + wo,
                bconv + bo, gamma + bo, beta + bo, hn, relu);
        } else {
            sage_tail2<1><<<fgrid, blk, 0, stream>>>(
                h, hp_b, off, esrc, wself_f + wo, wneigh_f + wo,
                bconv + bo, gamma + bo, beta + bo, d_out, relu);
        }
        unsigned short* tmp = h; h = hn; hn = tmp;
    }
}

// Round 10
// 545.394 us; speedup vs baseline: 1.2373x; 1.2373x over previous
//
#include <hip/hip_runtime.h>

// Problem constants (from reference)
#define N_NODES 20000
#define F_IN    512
#define D_H     256
#define E_EDGES 200000
#define L_LAYERS 3
#define T_ETYPES 2

typedef __attribute__((ext_vector_type(8))) short bf16x8;
typedef __attribute__((ext_vector_type(4))) float f32x4;

__device__ __forceinline__ unsigned short f2b(float f) {
    unsigned int u = __float_as_uint(f);
    u = (u + 0x7FFFu + ((u >> 16) & 1u)) >> 16;   // round-nearest-even
    return (unsigned short)u;
}
__device__ __forceinline__ unsigned int pack2(float a, float b) {
    return (unsigned int)f2b(a) | ((unsigned int)f2b(b) << 16);
}

// ---------------- weight pre-shuffle: fp32 row-major -> bf16 fragment-slab order ----
// For W[NO,K]: slab (n>>7, k>>5) of 128 rows x 32 k is a contiguous 4096-elem block;
// elem (n_local,kk) at ((n_local>>4)&7)<<9 | ((kk>>3)&3)<<7 | (n_local&15)<<3 | (kk&7).
// A wave's 16x32 B-tile t at step s is the 1KB run: slab + (t&7)*512 + lane*8.
__device__ __forceinline__ void shuf_one(const float* s, unsigned short* d,
                                         int NO, int K, int i)
{
    const int matsz = NO * K;
    const int mat = i / matsz;
    const int rem = i - mat * matsz;
    const int n = rem / K;
    const int k = rem - n * K;
    const int dst = mat * matsz + ((n >> 7) * (K >> 5) + (k >> 5)) * 4096
                  + (((n >> 4) & 7) << 9) + (((k >> 3) & 3) << 7)
                  + ((n & 15) << 3) + (k & 7);
    d[dst] = f2b(s[i]);
}

__global__ __launch_bounds__(256) void shufw_kernel(
    const float* __restrict__ s0, unsigned short* __restrict__ d0, int NO0, int K0, int n0,
    const float* __restrict__ s1, unsigned short* __restrict__ d1, int NO1, int K1, int n1,
    const float* __restrict__ s2, unsigned short* __restrict__ d2, int NO2, int K2, int n2,
    const float* __restrict__ s3, unsigned short* __restrict__ d3, int NO3, int K3, int n3)
{
    int i = blockIdx.x * 256 + threadIdx.x;
    if (i < n0) { shuf_one(s0, d0, NO0, K0, i); return; }
    if ((i -= n0) < n1) { shuf_one(s1, d1, NO1, K1, i); return; }
    if ((i -= n1) < n2) { shuf_one(s2, d2, NO2, K2, i); return; }
    if ((i -= n2) < n3) { shuf_one(s3, d3, NO3, K3, i); return; }
}

// ---------------- barrier-free GEMM, fragment-slab weights (lin / pool) ----------------
// C[M, bn:bn+128] = act(A @ W^T + bias). Block 64x128, 4 waves 2x2, wave 32x64.
// NO LDS, NO barriers: A and B fragments both stream global->VGPR (B coalesced 1KB/inst).
template <int A_FP32, int NSTEPS>
__global__ __launch_bounds__(256) void gemm_frag(
    const void* __restrict__ Ap, const unsigned short* __restrict__ Wf,
    const float* __restrict__ bias, unsigned short* __restrict__ Cout,
    int M, int ldc, int relu)
{
    const int K = NSTEPS * 32;
    const int tid  = threadIdx.x;
    const int lane = tid & 63;
    const int w    = tid >> 6;
    const int wm   = w >> 1, wn = w & 1;
    const int bm   = blockIdx.y * 64;
    const int bn   = blockIdx.x * 128;
    const unsigned short* slab0 = Wf + (size_t)blockIdx.x * NSTEPS * 4096;

    const int r0 = min(bm + wm * 32 + (lane & 15), M - 1);
    const int r1 = min(bm + wm * 32 + 16 + (lane & 15), M - 1);
    const int ko = (lane >> 4) << 3;

    f32x4 acc[2][4] = {};

    for (int s = 0; s < NSTEPS; ++s) {
        bf16x8 af0, af1;
        if (A_FP32) {
            const float* p0 = (const float*)Ap + (size_t)r0 * K + s * 32 + ko;
            const float* p1 = (const float*)Ap + (size_t)r1 * K + s * 32 + ko;
            const float4 a0 = *(const float4*)p0, a1 = *(const float4*)(p0 + 4);
            const float4 a2 = *(const float4*)p1, a3 = *(const float4*)(p1 + 4);
            uint4 u0, u1;
            u0.x = pack2(a0.x, a0.y); u0.y = pack2(a0.z, a0.w);
            u0.z = pack2(a1.x, a1.y); u0.w = pack2(a1.z, a1.w);
            u1.x = pack2(a2.x, a2.y); u1.y = pack2(a2.z, a2.w);
            u1.z = pack2(a3.x, a3.y); u1.w = pack2(a3.z, a3.w);
            af0 = *(bf16x8*)&u0; af1 = *(bf16x8*)&u1;
        } else {
            af0 = *(const bf16x8*)((const unsigned short*)Ap + (size_t)r0 * K + s * 32 + ko);
            af1 = *(const bf16x8*)((const unsigned short*)Ap + (size_t)r1 * K + s * 32 + ko);
        }
#pragma unroll
        for (int j = 0; j < 4; ++j) {
            const bf16x8 bf = *(const bf16x8*)(slab0 + s * 4096 + ((wn * 4 + j) << 9) + lane * 8);
            acc[0][j] = __builtin_amdgcn_mfma_f32_16x16x32_bf16(af0, bf, acc[0][j], 0, 0, 0);
            acc[1][j] = __builtin_amdgcn_mfma_f32_16x16x32_bf16(af1, bf, acc[1][j], 0, 0, 0);
        }
    }

    // C/D layout: col = lane&15, row = (lane>>4)*4 + reg
    const int cbase = bn + wn * 64 + (lane & 15);
    const int rbase = bm + wm * 32 + ((lane >> 4) << 2);
#pragma unroll
    for (int j = 0; j < 4; ++j) {
        const int col = cbase + j * 16;
        const float bj = bias[col];
#pragma unroll
        for (int i = 0; i < 2; ++i)
#pragma unroll
            for (int r = 0; r < 4; ++r) {
                const int row = rbase + i * 16 + r;
                if (row < M) {
                    float v = acc[i][j][r] + bj;
                    if (relu) v = fmaxf(v, 0.f);
                    Cout[(size_t)row * ldc + col] = f2b(v);
                }
            }
    }
}

// ---------------- fused layer tail, BOTH etypes: dual GEMM + ReLU + LN + sum ----------------
// out[row] = sum_e LN_e( maybe_relu( h@Ws_e^T + neigh_e@Wn_e^T + b_e ) )
// Block 32 rows x 256 cols, 4 waves (wave 32x64 per etype), grid 625 exact.
// Barrier-free K-loop; self A fragments loaded once, reused for both etypes.
// neigh read from global [N,512] (standalone seg-max output).
template <int OUT_FP32>
__global__ __launch_bounds__(256) void sage_tail2e(
    const unsigned short* __restrict__ h,      // [N,256] bf16
    const unsigned short* __restrict__ neigh,  // [N,512] bf16 (t*256 col offset)
    const unsigned short* __restrict__ Wfs,    // [2 mats][2 slabs x 8 steps x 4096]
    const unsigned short* __restrict__ Wfn,
    const float* __restrict__ bias2,           // [2,256]
    const float* __restrict__ gamma2, const float* __restrict__ beta2,
    void* __restrict__ outp, int relu)
{
    __shared__ float sS[2][4][32], sQ[2][4][32];
    const int tid  = threadIdx.x;
    const int lane = tid & 63;
    const int wv   = tid >> 6;
    const int bm   = blockIdx.x * 32;
    const int r0   = bm + (lane & 15);
    const int ko   = (lane >> 4) << 3;

    f32x4 acc[2][2][4] = {};   // [etype][mtile][ntile]

    // self pass: A = h (global), loaded once, used for both etypes' weights
#pragma unroll 2
    for (int s = 0; s < 8; ++s) {
        const bf16x8 af0 = *(const bf16x8*)(h + (size_t)r0 * D_H + s * 32 + ko);
        const bf16x8 af1 = *(const bf16x8*)(h + (size_t)(r0 + 16) * D_H + s * 32 + ko);
#pragma unroll
        for (int e = 0; e < 2; ++e)
#pragma unroll
            for (int j = 0; j < 4; ++j) {
                const int tt = wv * 4 + j;
                const bf16x8 bf = *(const bf16x8*)(Wfs + e * 65536
                    + (((tt >> 3) * 8 + s) << 12) + ((tt & 7) << 9) + lane * 8);
                acc[e][0][j] = __builtin_amdgcn_mfma_f32_16x16x32_bf16(af0, bf, acc[e][0][j], 0, 0, 0);
                acc[e][1][j] = __builtin_amdgcn_mfma_f32_16x16x32_bf16(af1, bf, acc[e][1][j], 0, 0, 0);
            }
    }
    // neigh pass: A_e = neigh[:, e*256 + ...] (global)
#pragma unroll 2
    for (int s = 0; s < 8; ++s) {
#pragma unroll
        for (int e = 0; e < 2; ++e) {
            const bf16x8 af0 = *(const bf16x8*)(neigh + (size_t)r0 * 512 + e * D_H + s * 32 + ko);
            const bf16x8 af1 = *(const bf16x8*)(neigh + (size_t)(r0 + 16) * 512 + e * D_H + s * 32 + ko);
#pragma unroll
            for (int j = 0; j < 4; ++j) {
                const int tt = wv * 4 + j;
                const bf16x8 bf = *(const bf16x8*)(Wfn + e * 65536
                    + (((tt >> 3) * 8 + s) << 12) + ((tt & 7) << 9) + lane * 8);
                acc[e][0][j] = __builtin_amdgcn_mfma_f32_16x16x32_bf16(af0, bf, acc[e][0][j], 0, 0, 0);
                acc[e][1][j] = __builtin_amdgcn_mfma_f32_16x16x32_bf16(af1, bf, acc[e][1][j], 0, 0, 0);
            }
        }
    }

    // Epilogue: per-etype LN over 256 cols, sum etypes, write.
    const int colb = wv * 64 + (lane & 15);
    const int rq   = (lane >> 4) << 2;
    float bia[2][4], gam[2][4], bet[2][4];
#pragma unroll
    for (int e = 0; e < 2; ++e)
#pragma unroll
        for (int j = 0; j < 4; ++j) {
            const int col = colb + j * 16;
            bia[e][j] = bias2[e * D_H + col];
            gam[e][j] = gamma2[e * D_H + col];
            bet[e][j] = beta2[e * D_H + col];
        }
#pragma unroll
    for (int e = 0; e < 2; ++e)
#pragma unroll
        for (int i = 0; i < 2; ++i)
#pragma unroll
            for (int r = 0; r < 4; ++r) {
                float s = 0.f, q = 0.f;
#pragma unroll
                for (int j = 0; j < 4; ++j) {
                    float v = acc[e][i][j][r] + bia[e][j];
                    if (relu) v = fmaxf(v, 0.f);
                    s += v; q += v * v;
                }
#pragma unroll
                for (int o = 1; o < 16; o <<= 1) {
                    s += __shfl_xor(s, o);
                    q += __shfl_xor(q, o);
                }
                if ((lane & 15) == 0) {
                    sS[e][wv][i * 16 + rq + r] = s;
                    sQ[e][wv][i * 16 + rq + r] = q;
                }
            }
    __syncthreads();
#pragma unroll
    for (int i = 0; i < 2; ++i)
#pragma unroll
        for (int r = 0; r < 4; ++r) {
            const int rl = i * 16 + rq + r;
            const int row = bm + rl;
            float mean[2], inv[2];
#pragma unroll
            for (int e = 0; e < 2; ++e) {
                const float st = sS[e][0][rl] + sS[e][1][rl] + sS[e][2][rl] + sS[e][3][rl];
                const float qt = sQ[e][0][rl] + sQ[e][1][rl] + sQ[e][2][rl] + sQ[e][3][rl];
                mean[e] = st * (1.f / 256.f);
                const float var = qt * (1.f / 256.f) - mean[e] * mean[e];
                inv[e] = rsqrtf(var + 1e-5f);
            }
#pragma unroll
            for (int j = 0; j < 4; ++j) {
                const int col = colb + j * 16;
                float o = 0.f;
#pragma unroll
                for (int e = 0; e < 2; ++e) {
                    float v = acc[e][i][j][r] + bia[e][j];
                    if (relu) v = fmaxf(v, 0.f);
                    o += (v - mean[e]) * inv[e] * gam[e][j] + bet[e][j];
                }
                if (OUT_FP32)
                    ((float*)outp)[(size_t)row * D_H + col] = o;
                else
                    ((unsigned short*)outp)[(size_t)row * D_H + col] = f2b(o);
            }
        }
}

// ---------------- CSR build (both etypes batched; once per launch) ----------------
__global__ __launch_bounds__(256) void zero_int_kernel(int* p, int n)
{
    int i = blockIdx.x * 256 + threadIdx.x;
    if (i < n) p[i] = 0;
}

__global__ __launch_bounds__(256) void count_deg_kernel(
    const int* __restrict__ dst, int* __restrict__ cnt, int E2)
{
    int e = blockIdx.x * 256 + threadIdx.x;
    if (e < E2) {
        const int base = (e >= E_EDGES) ? N_NODES : 0;
        atomicAdd(&cnt[base + dst[e]], 1);
    }
}

__global__ __launch_bounds__(256) void scanA_kernel(
    const int* __restrict__ cnt, int* __restrict__ incl, int* __restrict__ bsum, int n)
{
    __shared__ int tmp[256];
    const int tid = threadIdx.x;
    const int i = blockIdx.x * 256 + tid;
    const int v = (i < n) ? cnt[i] : 0;
    tmp[tid] = v;
    __syncthreads();
#pragma unroll
    for (int o = 1; o < 256; o <<= 1) {
        const int t = (tid >= o) ? tmp[tid - o] : 0;
        __syncthreads();
        tmp[tid] += t;
        __syncthreads();
    }
    if (i < n) incl[i] = tmp[tid];
    if (tid == 255) bsum[blockIdx.x] = tmp[255];
}

__global__ __launch_bounds__(256) void scanB_kernel(int* __restrict__ bsum, int nb)
{
    __shared__ int tmp[256];
    const int tid = threadIdx.x;
    const int v = (tid < nb) ? bsum[tid] : 0;
    tmp[tid] = v;
    __syncthreads();
#pragma unroll
    for (int o = 1; o < 256; o <<= 1) {
        const int t = (tid >= o) ? tmp[tid - o] : 0;
        __syncthreads();
        tmp[tid] += t;
        __syncthreads();
    }
    if (tid < nb) bsum[tid] = tmp[tid] - v;  // exclusive
}

__global__ __launch_bounds__(256) void scanC_kernel(
    const int* __restrict__ cnt, const int* __restrict__ incl,
    const int* __restrict__ bsum, int* __restrict__ off, int* __restrict__ cursor, int n)
{
    const int i = blockIdx.x * 256 + threadIdx.x;
    if (i < n) {
        const int e = incl[i] + bsum[blockIdx.x];
        off[i + 1] = e;
        cursor[i] = e - cnt[i];
    }
    if (i == 0) off[0] = 0;
}

__global__ __launch_bounds__(256) void fill_csr_kernel(
    const int* __restrict__ src, const int* __restrict__ dst,
    int* __restrict__ cursor, int* __restrict__ esrc, int E2)
{
    int e = blockIdx.x * 256 + threadIdx.x;
    if (e < E2) {
        const int base = (e >= E_EDGES) ? N_NODES : 0;
        const int pos = atomicAdd(&cursor[base + dst[e]], 1);
        esrc[pos] = src[e];
    }
}

// ---------------- segment max (bf16, both etypes): one wave per (node,t) ----------------
__device__ __forceinline__ ushort4 umax4(ushort4 a, ushort4 b)
{
    a.x = a.x > b.x ? a.x : b.x;
    a.y = a.y > b.y ? a.y : b.y;
    a.z = a.z > b.z ? a.z : b.z;
    a.w = a.w > b.w ? a.w : b.w;
    return a;
}

__global__ __launch_bounds__(256) void seg_max_kernel(
    const unsigned short* __restrict__ hp, const int* __restrict__ off,
    const int* __restrict__ esrc, unsigned short* __restrict__ neigh)
{
    const int g = blockIdx.x * 4 + (threadIdx.x >> 6);
    if (g >= 2 * N_NODES) return;
    const int t = (g >= N_NODES) ? 1 : 0;
    const int node = g - t * N_NODES;
    const int lane = threadIdx.x & 63;
    const int co = t * D_H + lane * 4;
    const int e0 = off[g], e1 = off[g + 1];
    ushort4 acc = make_ushort4(0, 0, 0, 0);
    int e = e0;
    for (; e + 4 <= e1; e += 4) {
        const int s0 = esrc[e + 0], s1 = esrc[e + 1];
        const int s2 = esrc[e + 2], s3 = esrc[e + 3];
        const ushort4 v0 = *(const ushort4*)(hp + (size_t)s0 * 512 + co);
        const ushort4 v1 = *(const ushort4*)(hp + (size_t)s1 * 512 + co);
        const ushort4 v2 = *(const ushort4*)(hp + (size_t)s2 * 512 + co);
        const ushort4 v3 = *(const ushort4*)(hp + (size_t)s3 * 512 + co);
        acc = umax4(umax4(umax4(acc, v0), umax4(v1, v2)), v3);
    }
    for (; e < e1; ++e)
        acc = umax4(acc, *(const ushort4*)(hp + (size_t)esrc[e] * 512 + co));
    *(ushort4*)(neigh + (size_t)node * 512 + co) = acc;
}

extern "C" void kernel_launch(void* const* d_in, const int* in_sizes, int n_in,
                              void* d_out, int out_size, void* d_ws, size_t ws_size,
                              hipStream_t stream)
{
    const float* x      = (const float*)d_in[0];
    const int*   src    = (const int*)d_in[1];
    const int*   dst    = (const int*)d_in[2];
    const float* Wlin   = (const float*)d_in[3];
    const float* blin   = (const float*)d_in[4];
    const float* Wpool  = (const float*)d_in[5];
    const float* bpool  = (const float*)d_in[6];
    const float* Wself  = (const float*)d_in[7];
    const float* Wneigh = (const float*)d_in[8];
    const float* bconv  = (const float*)d_in[9];
    const float* gamma  = (const float*)d_in[10];
    const float* beta   = (const float*)d_in[11];

    const size_t NB = (size_t)N_NODES * D_H;  // 5.12M
    char* p = (char*)d_ws;
    unsigned short* hp_b    = (unsigned short*)p; p += NB * 2 * T_ETYPES;  // [N,512]
    unsigned short* neigh_b = (unsigned short*)p; p += NB * 2 * T_ETYPES;  // [N,512]
    unsigned short* h_a     = (unsigned short*)p; p += NB * 2;
    unsigned short* h_b     = (unsigned short*)p; p += NB * 2;
    unsigned short* wlin_f  = (unsigned short*)p; p += (size_t)D_H * F_IN * 2;
    const size_t WSZ = (size_t)L_LAYERS * T_ETYPES * D_H * D_H;  // 393216
    unsigned short* wpool_f = (unsigned short*)p; p += WSZ * 2;
    unsigned short* wself_f = (unsigned short*)p; p += WSZ * 2;
    unsigned short* wneigh_f= (unsigned short*)p; p += WSZ * 2;
    int* ip = (int*)p;
    const int NT = T_ETYPES * N_NODES;  // 40000
    int* cnt    = ip; ip += NT;
    int* incl   = ip; ip += NT;
    int* off    = ip; ip += NT + 1;
    int* cursor = ip; ip += NT;
    int* esrc   = ip; ip += T_ETYPES * E_EDGES;
    int* bsum   = ip; ip += 256;

    const dim3 blk(256);
    const int E2 = T_ETYPES * E_EDGES;
    const dim3 e2grid((E2 + 255) / 256);
    const dim3 ntgrid((NT + 255) / 256);
    const int nScanBlk = (NT + 255) / 256;  // 157

    // ---- weights -> bf16 fragment-slab order (one dispatch) ----
    {
        const int nlin = D_H * F_IN;          // 131072, NO=256 K=512
        const int nw   = (int)WSZ;            // 393216
        const int tot  = nlin + 3 * nw;
        shufw_kernel<<<dim3((tot + 255) / 256), blk, 0, stream>>>(
            Wlin, wlin_f, D_H, F_IN, nlin,
            Wpool, wpool_f, T_ETYPES * D_H, D_H, nw,   // per layer: [512,256]
            Wself, wself_f, D_H, D_H, nw,              // per (l,t): [256,256]
            Wneigh, wneigh_f, D_H, D_H, nw);
    }

    // ---- CSR build, both etypes batched ----
    zero_int_kernel<<<ntgrid, blk, 0, stream>>>(cnt, NT);
    count_deg_kernel<<<e2grid, blk, 0, stream>>>(dst, cnt, E2);
    scanA_kernel<<<dim3(nScanBlk), blk, 0, stream>>>(cnt, incl, bsum, NT);
    scanB_kernel<<<dim3(1), blk, 0, stream>>>(bsum, nScanBlk);
    scanC_kernel<<<dim3(nScanBlk), blk, 0, stream>>>(cnt, incl, bsum, off, cursor, NT);
    fill_csr_kernel<<<e2grid, blk, 0, stream>>>(src, dst, cursor, esrc, E2);

    // ---- h0 = bf16(x @ Wlin^T + blin) : fp32 A fused-convert, K=512 ----
    gemm_frag<1, 16><<<dim3(2, (N_NODES + 63) / 64), blk, 0, stream>>>(
        x, wlin_f, blin, h_a, N_NODES, D_H, 0);

    unsigned short* h = h_a;
    unsigned short* hn = h_b;
    const dim3 pgrid(4, (N_NODES + 63) / 64);   // pool: 512 cols batched over etypes
    const dim3 sgrid((2 * N_NODES + 3) / 4);
    const dim3 fgrid(N_NODES / 32);             // 625, exact
    for (int l = 0; l < L_LAYERS; ++l) {
        const int relu = (l < L_LAYERS - 1) ? 1 : 0;
        const size_t wo = (size_t)l * T_ETYPES * D_H * D_H;
        const size_t bo = (size_t)l * T_ETYPES * D_H;
        // hp[:, t*256:] = bf16(relu(h @ Wpool[l,t]^T + bpool[l,t])), both t in one dispatch
        gemm_frag<0, 8><<<pgrid, blk, 0, stream>>>(
            h, wpool_f + wo, bpool + bo, hp_b, N_NODES, T_ETYPES * D_H, 1);
        // neigh = segment_max per (node, t): one wave per task, massively parallel
        seg_max_kernel<<<sgrid, blk, 0, stream>>>(hp_b, off, esrc, neigh_b);
        // fused: both etypes' dual GEMM + relu + per-etype LN + sum (barrier-free K-loop)
        if (l < L_LAYERS - 1) {
            sage_tail2e<0><<<fgrid, blk, 0, stream>>>(
                h, neigh_b, wself_f + wo, wneigh_f + wo,
                bconv + bo, gamma + bo, beta + bo, hn, relu);
        } else {
            sage_tail2e<1><<<fgrid, blk, 0, stream>>>(
                h, neigh_b, wself_f + wo, wneigh_f + wo,
                bconv + bo, gamma + bo, beta + bo, d_out, relu);
        }
        unsigned short* tmp = h; h = hn; hn = tmp;
    }
}